// Round 6
// baseline (84.930 us; speedup 1.0000x reference)
//
#include <hip/hip_runtime.h>
#include <math.h>

// PartialAttention: LN -> Q/K proj -> scaled QK^T -> rowmax-subtracted exp.
// S=4096, B=2, E=1024, D=64. Out [B,S,S] f32 = 134 MB.
//
// Pipeline:
//  W (wprep):   W -> bf16 RNE hi/lo B-frag arrays (verbatim r5, proven).
//  A (ln_split):LN stats + normalize + RNE hi/lo split -> global A-frag
//               arrays xh/xl (16 MB each), conversion once per element.
//  B (proj):    split-K=4, 32 rows/block, 8 waves; A-frags LDS-staged once,
//               W-frags from L2; 4-term hi/lo MFMA; f32 partial-C frags.
//  R (reduce):  sum 4 partials + bias -> f32 qk LDS tile (r5 layout) ->
//               verbatim proven phase-3 splitter -> q/k frag arrays.
//  S (score):   verbatim r2/r5 (write-roofline).

typedef __attribute__((ext_vector_type(4))) float f32x4;
typedef __attribute__((ext_vector_type(8))) short bf16x8;
typedef __attribute__((ext_vector_type(8))) unsigned short u16x8;

#define SLEN 4096
#define BATCH 2
#define EDIM 1024
#define DDIM 64
#define QK_STRIDE 136    // q cols [0,64), k cols [68,132)

__device__ __forceinline__ unsigned short f2bf(float f) {
    unsigned int u = __float_as_uint(f);
    u += 0x7FFFu + ((u >> 16) & 1u);   // RNE to bf16
    return (unsigned short)(u >> 16);
}
__device__ __forceinline__ float bf2f(unsigned short h) {
    return __uint_as_float(((unsigned int)h) << 16);
}

// ---------------- kernel W: W fragment prep (verbatim r5, proven) ----------------
// slot = (ct*32 + kg)*64 + l; value j = W[kg*32 + ((l>>4)&3)*8 + j][ct*16 + (l&15)]
__global__ __launch_bounds__(256) void wprep_kernel(
    const float* __restrict__ Wq, const float* __restrict__ Wk,
    unsigned short* __restrict__ whf, unsigned short* __restrict__ wlf)
{
    const int slot = blockIdx.x * 256 + threadIdx.x;   // 0..16383
    const int ct = slot >> 11;
    const int kg = (slot >> 6) & 31;
    const int l  = slot & 63;
    const int c  = ct * 16 + (l & 15);
    const int kb = kg * 32 + ((l >> 4) & 3) * 8;
    const float* Wm = (c < DDIM) ? (Wq + c) : (Wk + (c - DDIM));
    u16x8 hv, lv;
#pragma unroll
    for (int j = 0; j < 8; ++j) {
        const float v = Wm[(size_t)(kb + j) * DDIM];
        const unsigned short h = f2bf(v);
        hv[j] = h;
        lv[j] = f2bf(v - bf2f(h));
    }
    *reinterpret_cast<u16x8*>(whf + (size_t)slot * 8) = hv;
    *reinterpret_cast<u16x8*>(wlf + (size_t)slot * 8) = lv;
}

// ---------------- kernel A: LN + split to global A-frags ----------------
// xh/xl slot = (gt*32 + kg)*64 + lane; value j = xnorm[s0 + (lane&15)]
//   [kg*32 + ((lane>>4)&3)*8 + j], gt = b*256 + tile.
__global__ __launch_bounds__(256, 2) void ln_split_kernel(
    const float* __restrict__ src, const float* __restrict__ gamma,
    const float* __restrict__ beta,
    unsigned short* __restrict__ xh, unsigned short* __restrict__ xl)
{
    __shared__ float2 stats[16];
    const int tid  = threadIdx.x;
    const int lane = tid & 63;
    const int wv   = tid >> 6;
    const int gt   = blockIdx.x;           // 0..511
    const int b    = gt >> 8;
    const int s0   = (gt & 255) * 16;

    // stats (verbatim proven): 4 rows per wave
    for (int ii = 0; ii < 4; ++ii) {
        const int i = wv * 4 + ii;
        const float* row = src + ((size_t)(s0 + i) * BATCH + b) * EDIM;
        float sum = 0.f, sq = 0.f;
#pragma unroll
        for (int k = 0; k < 4; ++k) {
            float4 v = *reinterpret_cast<const float4*>(row + k * 256 + lane * 4);
            sum += v.x + v.y + v.z + v.w;
            sq  += v.x*v.x + v.y*v.y + v.z*v.z + v.w*v.w;
        }
#pragma unroll
        for (int off = 1; off < 64; off <<= 1) {
            sum += __shfl_xor(sum, off);
            sq  += __shfl_xor(sq,  off);
        }
        if (lane == 0) {
            const float mu   = sum * (1.f / EDIM);
            const float rstd = rsqrtf(sq * (1.f / EDIM) - mu * mu + 1e-5f);
            stats[i] = make_float2(mu, rstd);
        }
    }
    __syncthreads();

    // split: thread handles 8 frag slots (kg = (tid>>6)*8 + i)
    const int row = lane & 15;
    const int k4  = ((lane >> 4) & 3) * 8;
    const float* srow = src + ((size_t)(s0 + row) * BATCH + b) * EDIM;
    const float mu   = stats[row].x;
    const float rstd = stats[row].y;
#pragma unroll
    for (int i = 0; i < 8; ++i) {
        const int kg = wv * 8 + i;
        const int kb = kg * 32 + k4;
        const float4 va = *reinterpret_cast<const float4*>(srow + kb);
        const float4 vb = *reinterpret_cast<const float4*>(srow + kb + 4);
        const float4 ga = *reinterpret_cast<const float4*>(gamma + kb);
        const float4 gb = *reinterpret_cast<const float4*>(gamma + kb + 4);
        const float4 ba = *reinterpret_cast<const float4*>(beta + kb);
        const float4 bb = *reinterpret_cast<const float4*>(beta + kb + 4);
        const float vv[8] = {
            (va.x - mu) * rstd * ga.x + ba.x, (va.y - mu) * rstd * ga.y + ba.y,
            (va.z - mu) * rstd * ga.z + ba.z, (va.w - mu) * rstd * ga.w + ba.w,
            (vb.x - mu) * rstd * gb.x + bb.x, (vb.y - mu) * rstd * gb.y + bb.y,
            (vb.z - mu) * rstd * gb.z + bb.z, (vb.w - mu) * rstd * gb.w + bb.w };
        u16x8 hv, lv;
#pragma unroll
        for (int j = 0; j < 8; ++j) {
            const unsigned short h = f2bf(vv[j]);
            hv[j] = h;
            lv[j] = f2bf(vv[j] - bf2f(h));
        }
        const size_t slot = ((size_t)gt * 32 + kg) * 64 + lane;
        *reinterpret_cast<u16x8*>(xh + slot * 8) = hv;
        *reinterpret_cast<u16x8*>(xl + slot * 8) = lv;
    }
}

// ---------------- kernel B: MFMA projection, split-K=4 ----------------
// block = (mg, ksl): rows of gt0=mg*2 and gt0+1, k-slice ksl (8 kg).
// 8 waves, wave wv = col-tile ct. Partial C frag:
//   pc[(((gt*4)+ksl)*8 + ct)*64 + lane] * 4 floats (C layout: col=lane&15,
//   row=(lane>>4)*4+r).
__global__ __launch_bounds__(512, 4) void proj_kernel(
    const unsigned short* __restrict__ xh, const unsigned short* __restrict__ xl,
    const unsigned short* __restrict__ whf, const unsigned short* __restrict__ wlf,
    float* __restrict__ pc)
{
    __shared__ u16x8 sa[2][2][8][64];      // [hl][t2][kg][lane], 32 KB
    const int tid  = threadIdx.x;
    const int lane = tid & 63;
    const int ct   = tid >> 6;             // wave = col-tile 0..7
    const int bid  = blockIdx.x;           // 0..1023
    const int mg   = bid >> 2;             // 0..255
    const int ksl  = bid & 3;
    const int gt0  = mg * 2;

    // stage A-frags for both tiles, this k-slice: 2048 u16x8 slots / 512 thr
    u16x8* sl = &sa[0][0][0][0];
#pragma unroll
    for (int p = 0; p < 4; ++p) {
        const int sidx = p * 512 + tid;
        const int hl   = sidx >> 10;
        const int rem  = sidx & 1023;
        const int t2   = rem >> 9;
        const int kg   = (rem >> 6) & 7;
        const int ln   = rem & 63;
        const size_t gslot = (((size_t)(gt0 + t2)) * 32 + ksl * 8 + kg) * 64 + ln;
        const unsigned short* srcp = hl ? xl : xh;
        sl[sidx] = *reinterpret_cast<const u16x8*>(srcp + gslot * 8);
    }
    __syncthreads();

    f32x4 acc0 = {0.f, 0.f, 0.f, 0.f};
    f32x4 acc1 = {0.f, 0.f, 0.f, 0.f};
#pragma unroll
    for (int kg = 0; kg < 8; ++kg) {
        const bf16x8 ah0 = *reinterpret_cast<const bf16x8*>(&sa[0][0][kg][lane]);
        const bf16x8 al0 = *reinterpret_cast<const bf16x8*>(&sa[1][0][kg][lane]);
        const bf16x8 ah1 = *reinterpret_cast<const bf16x8*>(&sa[0][1][kg][lane]);
        const bf16x8 al1 = *reinterpret_cast<const bf16x8*>(&sa[1][1][kg][lane]);
        const size_t wslot = ((size_t)ct * 32 + ksl * 8 + kg) * 64 + lane;
        const bf16x8 bh = *reinterpret_cast<const bf16x8*>(whf + wslot * 8);
        const bf16x8 bl = *reinterpret_cast<const bf16x8*>(wlf + wslot * 8);
        acc0 = __builtin_amdgcn_mfma_f32_16x16x32_bf16(ah0, bh, acc0, 0, 0, 0);
        acc1 = __builtin_amdgcn_mfma_f32_16x16x32_bf16(ah1, bh, acc1, 0, 0, 0);
        acc0 = __builtin_amdgcn_mfma_f32_16x16x32_bf16(al0, bh, acc0, 0, 0, 0);
        acc1 = __builtin_amdgcn_mfma_f32_16x16x32_bf16(al1, bh, acc1, 0, 0, 0);
        acc0 = __builtin_amdgcn_mfma_f32_16x16x32_bf16(ah0, bl, acc0, 0, 0, 0);
        acc1 = __builtin_amdgcn_mfma_f32_16x16x32_bf16(ah1, bl, acc1, 0, 0, 0);
        acc0 = __builtin_amdgcn_mfma_f32_16x16x32_bf16(al0, bl, acc0, 0, 0, 0);
        acc1 = __builtin_amdgcn_mfma_f32_16x16x32_bf16(al1, bl, acc1, 0, 0, 0);
    }
    {
        const size_t p0 = ((((size_t)gt0 * 4) + ksl) * 8 + ct) * 64 + lane;
        const size_t p1 = ((((size_t)(gt0 + 1) * 4) + ksl) * 8 + ct) * 64 + lane;
        float4 o0 = {acc0[0], acc0[1], acc0[2], acc0[3]};
        float4 o1 = {acc1[0], acc1[1], acc1[2], acc1[3]};
        *reinterpret_cast<float4*>(pc + p0 * 4) = o0;
        *reinterpret_cast<float4*>(pc + p1 * 4) = o1;
    }
}

// ---------------- kernel R: reduce partials + bias + split ----------------
__global__ __launch_bounds__(256, 2) void reduce_kernel(
    const float* __restrict__ pc,
    const float* __restrict__ bq, const float* __restrict__ bk,
    unsigned short* __restrict__ qhf, unsigned short* __restrict__ qlf,
    unsigned short* __restrict__ khf, unsigned short* __restrict__ klf)
{
    __shared__ float qk[16 * QK_STRIDE];   // 8.5 KB, r5 layout
    const int tid  = threadIdx.x;
    const int lane = tid & 63;
    const int wv   = tid >> 6;
    const int gt   = blockIdx.x;           // 0..511
    const int b    = gt >> 8;

    // sum 4 k-slices for col-tiles {2wv, 2wv+1}; bias; write qk tile
#pragma unroll
    for (int cti = 0; cti < 2; ++cti) {
        const int ct = wv * 2 + cti;
        float4 s = {0.f, 0.f, 0.f, 0.f};
#pragma unroll
        for (int ksl = 0; ksl < 4; ++ksl) {
            const size_t p = ((((size_t)gt * 4) + ksl) * 8 + ct) * 64 + lane;
            const float4 v = *reinterpret_cast<const float4*>(pc + p * 4);
            s.x += v.x; s.y += v.y; s.z += v.z; s.w += v.w;
        }
        const int cj = ct * 16 + (lane & 15);
        const int r0 = (lane >> 4) * 4;
        const float bv = (cj < DDIM) ? bq[cj] : bk[cj - DDIM];
        const int cb = (cj < DDIM) ? cj : (68 + cj - DDIM);
        qk[(r0 + 0) * QK_STRIDE + cb] = s.x + bv;
        qk[(r0 + 1) * QK_STRIDE + cb] = s.y + bv;
        qk[(r0 + 2) * QK_STRIDE + cb] = s.z + bv;
        qk[(r0 + 3) * QK_STRIDE + cb] = s.w + bv;
    }
    __syncthreads();

    // phase-3 (verbatim r2/r5, proven): RNE hi/lo split to frag order
    {
        const int l2  = tid & 63;
        const int dc  = (tid >> 6) & 1;
        const int isK = tid >> 7;
        const int row = l2 & 15;
        const int d0  = dc * 32 + ((l2 >> 4) & 3) * 8;
        const float* p = &qk[row * QK_STRIDE + (isK ? 68 : 0) + d0];
        const float sc = isK ? 1.0f : 0.125f;   // fold 1/sqrt(D) into q
        u16x8 hvv, lvv;
#pragma unroll
        for (int j = 0; j < 8; ++j) {
            const float vq = p[j] * sc;
            const unsigned short h = f2bf(vq);
            hvv[j] = h;
            lvv[j] = f2bf(vq - bf2f(h));
        }
        const size_t base = ((((size_t)b * 256 + (size_t)(gt & 255)) * 2 + dc) * 512) + (size_t)l2 * 8;
        *reinterpret_cast<u16x8*>((isK ? khf : qhf) + base) = hvv;
        *reinterpret_cast<u16x8*>((isK ? klf : qlf) + base) = lvv;
    }
}

// ---------------- kernel S: QK^T + rowmax + exp (verbatim r2/r5) ----------------
__global__ __launch_bounds__(1024, 1) void score_kernel(
    const unsigned short* __restrict__ qhf, const unsigned short* __restrict__ qlf,
    const unsigned short* __restrict__ khf, const unsigned short* __restrict__ klf,
    float* __restrict__ out)
{
    __shared__ float wmax[16 * 16];
    __shared__ float fmax_s[16];
    const int tid = threadIdx.x;
    const int l   = tid & 63;
    const int w   = tid >> 6;        // wave 0..15, owns col-tiles w*16..w*16+15
    const int bid = blockIdx.x;
    const int b   = bid >> 8;
    const int rt  = bid & 255;       // row tile (16 q rows)

    const size_t abase = (((size_t)b * 256 + rt) * 2) * 512 + (size_t)l * 8;
    const bf16x8 qh0 = *reinterpret_cast<const bf16x8*>(qhf + abase);
    const bf16x8 qh1 = *reinterpret_cast<const bf16x8*>(qhf + abase + 512);
    const bf16x8 ql0 = *reinterpret_cast<const bf16x8*>(qlf + abase);
    const bf16x8 ql1 = *reinterpret_cast<const bf16x8*>(qlf + abase + 512);

    f32x4 acc[16];
#pragma unroll
    for (int i = 0; i < 16; ++i) acc[i] = (f32x4){0.f, 0.f, 0.f, 0.f};

#pragma unroll
    for (int i = 0; i < 16; ++i) {
        const int ct = w * 16 + i;
        const size_t kb = (((size_t)b * 256 + ct) * 2) * 512 + (size_t)l * 8;
        const bf16x8 kh0 = *reinterpret_cast<const bf16x8*>(khf + kb);
        const bf16x8 kh1 = *reinterpret_cast<const bf16x8*>(khf + kb + 512);
        const bf16x8 kl0 = *reinterpret_cast<const bf16x8*>(klf + kb);
        const bf16x8 kl1 = *reinterpret_cast<const bf16x8*>(klf + kb + 512);
        f32x4 a = acc[i];
        a = __builtin_amdgcn_mfma_f32_16x16x32_bf16(qh0, kh0, a, 0, 0, 0);
        a = __builtin_amdgcn_mfma_f32_16x16x32_bf16(qh1, kh1, a, 0, 0, 0);
        a = __builtin_amdgcn_mfma_f32_16x16x32_bf16(qh0, kl0, a, 0, 0, 0);
        a = __builtin_amdgcn_mfma_f32_16x16x32_bf16(qh1, kl1, a, 0, 0, 0);
        a = __builtin_amdgcn_mfma_f32_16x16x32_bf16(ql0, kh0, a, 0, 0, 0);
        a = __builtin_amdgcn_mfma_f32_16x16x32_bf16(ql1, kh1, a, 0, 0, 0);
        acc[i] = a;
    }

    float m4[4];
#pragma unroll
    for (int r = 0; r < 4; ++r) {
        m4[r] = acc[0][r];
#pragma unroll
        for (int i = 1; i < 16; ++i) m4[r] = fmaxf(m4[r], acc[i][r]);
    }
#pragma unroll
    for (int off = 1; off < 16; off <<= 1) {
#pragma unroll
        for (int r = 0; r < 4; ++r) m4[r] = fmaxf(m4[r], __shfl_xor(m4[r], off));
    }
    const int rgrp = l >> 4;
    if ((l & 15) == 0) {
#pragma unroll
        for (int r = 0; r < 4; ++r) wmax[w * 16 + rgrp * 4 + r] = m4[r];
    }
    __syncthreads();
    if (tid < 16) {
        float m = wmax[tid];
#pragma unroll
        for (int ww = 1; ww < 16; ++ww) m = fmaxf(m, wmax[ww * 16 + tid]);
        fmax_s[tid] = m;
    }
    __syncthreads();

    float fm[4];
#pragma unroll
    for (int r = 0; r < 4; ++r) fm[r] = fmax_s[rgrp * 4 + r];
    const int cres = l & 15;
    const size_t obase = ((size_t)b * SLEN + (size_t)rt * 16) * SLEN;
#pragma unroll
    for (int i = 0; i < 16; ++i) {
        const int col = (w * 16 + i) * 16 + cres;
#pragma unroll
        for (int r = 0; r < 4; ++r)
            out[obase + (size_t)(rgrp * 4 + r) * SLEN + col] = __expf(acc[i][r] - fm[r]);
    }
}

extern "C" void kernel_launch(void* const* d_in, const int* in_sizes, int n_in,
                              void* d_out, int out_size, void* d_ws, size_t ws_size,
                              hipStream_t stream) {
    (void)in_sizes; (void)n_in;
    const float* src   = (const float*)d_in[0];
    const float* gamma = (const float*)d_in[1];
    const float* beta  = (const float*)d_in[2];
    const float* Wq    = (const float*)d_in[3];
    const float* bq    = (const float*)d_in[4];
    const float* Wk    = (const float*)d_in[5];
    const float* bk    = (const float*)d_in[6];
    float* out = (float*)d_out;

    // q/k frag arrays: 4 MB in ws (ws_size >= 4 MB proven by rounds 2-5).
    unsigned short* ws  = (unsigned short*)d_ws;
    unsigned short* qhf = ws;
    unsigned short* qlf = ws + (1u << 19);
    unsigned short* khf = ws + (2u << 19);
    unsigned short* klf = ws + (3u << 19);

    // big scratch: whf/wlf (256 KB ea) + xh/xl (16 MB ea) + pc (16 MB)
    const size_t WF = 131072;        // shorts per W frag array
    const size_t XF = 8388608;       // shorts per x frag array (16 MB)
    const size_t big_bytes = 2 * WF * 2 + 2 * XF * 2 + (size_t)4194304 * 4; // 512K + 32M + 16M
    const size_t need = (4u << 20) + big_bytes;
    unsigned short *whf, *wlf, *xh, *xl;
    float* pc;
    if (ws_size >= need) {
        whf = ws + (4u << 19);
        wlf = whf + WF;
        xh  = wlf + WF;
        xl  = xh + XF;
        pc  = (float*)(xl + XF);
    } else {
        // park in d_out tail: written by W/A/B, consumed by B/R, then fully
        // overwritten by S (stream-ordered sequential kernels -> safe).
        const size_t out_bytes = (size_t)out_size * 4;
        size_t base = (out_bytes - big_bytes) & ~(size_t)255;
        char* tp = (char*)d_out + base;
        whf = (unsigned short*)tp;            tp += WF * 2;
        wlf = (unsigned short*)tp;            tp += WF * 2;
        xh  = (unsigned short*)tp;            tp += XF * 2;
        xl  = (unsigned short*)tp;            tp += XF * 2;
        pc  = (float*)tp;
    }

    hipLaunchKernelGGL(wprep_kernel, dim3(64), dim3(256), 0, stream,
                       Wq, Wk, whf, wlf);
    hipLaunchKernelGGL(ln_split_kernel, dim3(512), dim3(256), 0, stream,
                       src, gamma, beta, xh, xl);
    hipLaunchKernelGGL(proj_kernel, dim3(1024), dim3(512), 0, stream,
                       xh, xl, whf, wlf, pc);
    hipLaunchKernelGGL(reduce_kernel, dim3(512), dim3(256), 0, stream,
                       pc, bq, bk, qhf, qlf, khf, klf);
    hipLaunchKernelGGL(score_kernel, dim3(512), dim3(1024), 0, stream,
                       qhf, qlf, khf, klf, out);
}

// Round 7
// 73.366 us; speedup vs baseline: 1.1576x; 1.1576x over previous
//
#include <hip/hip_runtime.h>
#include <math.h>

// PartialAttention: LN -> Q/K proj -> scaled QK^T -> rowmax-subtracted exp.
// S=4096, B=2, E=1024, D=64. Out [B,S,S] f32 = 134 MB.
//
// Kernel W (wprep): W -> bf16 RNE hi/lo B-frag arrays (verbatim r5, proven).
// Kernel 1 (ln_proj): fused, 512 thr (8 waves), 16 rows/block.
//   Stats (shfl) -> per-chunk: staging threads normalize + RNE hi/lo split
//   DIRECTLY into fragment-ordered LDS (each element converted once),
//   double-buffered; 8 waves each own one col-tile: ds_read A-frags,
//   L2-stream B-frags, 4-term hi/lo MFMA (r5-proven algebra) -> bias ->
//   f32 qk LDS tile -> verbatim proven phase-3 splitter.
// Kernel S (score): verbatim r2/r5 (write-roofline).

typedef __attribute__((ext_vector_type(4))) float f32x4;
typedef __attribute__((ext_vector_type(8))) short bf16x8;
typedef __attribute__((ext_vector_type(8))) unsigned short u16x8;

#define SLEN 4096
#define BATCH 2
#define EDIM 1024
#define DDIM 64
#define QK_STRIDE 136    // q cols [0,64), k cols [68,132)

__device__ __forceinline__ unsigned short f2bf(float f) {
    unsigned int u = __float_as_uint(f);
    u += 0x7FFFu + ((u >> 16) & 1u);   // RNE to bf16
    return (unsigned short)(u >> 16);
}
__device__ __forceinline__ float bf2f(unsigned short h) {
    return __uint_as_float(((unsigned int)h) << 16);
}

// ---------------- kernel W: W fragment prep (verbatim r5, proven) ----------------
// slot = (ct*32 + kg)*64 + l; value j = W[kg*32 + ((l>>4)&3)*8 + j][ct*16 + (l&15)]
__global__ __launch_bounds__(256) void wprep_kernel(
    const float* __restrict__ Wq, const float* __restrict__ Wk,
    unsigned short* __restrict__ whf, unsigned short* __restrict__ wlf)
{
    const int slot = blockIdx.x * 256 + threadIdx.x;   // 0..16383
    const int ct = slot >> 11;
    const int kg = (slot >> 6) & 31;
    const int l  = slot & 63;
    const int c  = ct * 16 + (l & 15);
    const int kb = kg * 32 + ((l >> 4) & 3) * 8;
    const float* Wm = (c < DDIM) ? (Wq + c) : (Wk + (c - DDIM));
    u16x8 hv, lv;
#pragma unroll
    for (int j = 0; j < 8; ++j) {
        const float v = Wm[(size_t)(kb + j) * DDIM];
        const unsigned short h = f2bf(v);
        hv[j] = h;
        lv[j] = f2bf(v - bf2f(h));
    }
    *reinterpret_cast<u16x8*>(whf + (size_t)slot * 8) = hv;
    *reinterpret_cast<u16x8*>(wlf + (size_t)slot * 8) = lv;
}

// ---------------- kernel 1: LN + MFMA projection (fused, 8 waves) ----------------
__global__ __launch_bounds__(512, 2) void ln_proj_kernel(
    const float* __restrict__ src, const float* __restrict__ gamma,
    const float* __restrict__ beta,
    const float* __restrict__ bq, const float* __restrict__ bk,
    const unsigned short* __restrict__ whf, const unsigned short* __restrict__ wlf,
    unsigned short* __restrict__ qhf, unsigned short* __restrict__ qlf,
    unsigned short* __restrict__ khf, unsigned short* __restrict__ klf)
{
    __shared__ u16x8 xhf[2][8][64];        // 16 KB: A-frag hi, dbuf per chunk
    __shared__ u16x8 xlf[2][8][64];        // 16 KB: A-frag lo
    __shared__ float2 stats[16];
    __shared__ float qk[16 * QK_STRIDE];   // 8.7 KB
    const int tid  = threadIdx.x;
    const int lane = tid & 63;
    const int wv   = tid >> 6;             // 0..7
    const int gt   = blockIdx.x;           // 0..511
    const int b    = gt >> 8;
    const int s0   = (gt & 255) * 16;

    // ---- phase A: LN stats, 2 rows per wave (proven reduce) ----
    for (int ii = 0; ii < 2; ++ii) {
        const int i = wv * 2 + ii;
        const float* row = src + ((size_t)(s0 + i) * BATCH + b) * EDIM;
        float sum = 0.f, sq = 0.f;
#pragma unroll
        for (int k = 0; k < 4; ++k) {
            float4 v = *reinterpret_cast<const float4*>(row + k * 256 + lane * 4);
            sum += v.x + v.y + v.z + v.w;
            sq  += v.x*v.x + v.y*v.y + v.z*v.z + v.w*v.w;
        }
#pragma unroll
        for (int off = 1; off < 64; off <<= 1) {
            sum += __shfl_xor(sum, off);
            sq  += __shfl_xor(sq,  off);
        }
        if (lane == 0) {
            const float mu   = sum * (1.f / EDIM);
            const float rstd = rsqrtf(sq * (1.f / EDIM) - mu * mu + 1e-5f);
            stats[i] = make_float2(mu, rstd);
        }
    }
    __syncthreads();

    // staging role: thread -> frag slot (kg = wv, lane); reads 8 floats of
    // row (lane&15) at col c*256 + wv*32 + (lane>>4)*8; wave covers 16 rows
    // x 128 B fully (sector-coalesced).
    const int srow = lane & 15;
    const int scol = wv * 32 + (lane >> 4) * 8;
    const float* srcrow = src + ((size_t)(s0 + srow) * BATCH + b) * EDIM;
    const float smu = stats[srow].x;
    const float srs = stats[srow].y;

#define STAGE(c, bf)                                                          \
    {                                                                         \
        const int cb_ = (c) * 256 + scol;                                     \
        const float4 va = *reinterpret_cast<const float4*>(srcrow + cb_);     \
        const float4 vb = *reinterpret_cast<const float4*>(srcrow + cb_ + 4); \
        const float4 ga = *reinterpret_cast<const float4*>(gamma + cb_);      \
        const float4 gb = *reinterpret_cast<const float4*>(gamma + cb_ + 4);  \
        const float4 ba = *reinterpret_cast<const float4*>(beta + cb_);       \
        const float4 bb = *reinterpret_cast<const float4*>(beta + cb_ + 4);   \
        const float vv[8] = {                                                 \
            (va.x - smu) * srs * ga.x + ba.x, (va.y - smu) * srs * ga.y + ba.y,\
            (va.z - smu) * srs * ga.z + ba.z, (va.w - smu) * srs * ga.w + ba.w,\
            (vb.x - smu) * srs * gb.x + bb.x, (vb.y - smu) * srs * gb.y + bb.y,\
            (vb.z - smu) * srs * gb.z + bb.z, (vb.w - smu) * srs * gb.w + bb.w };\
        u16x8 hv, lv;                                                         \
        _Pragma("unroll")                                                     \
        for (int j = 0; j < 8; ++j) {                                         \
            const unsigned short h = f2bf(vv[j]);                             \
            hv[j] = h;                                                        \
            lv[j] = f2bf(vv[j] - bf2f(h));                                    \
        }                                                                     \
        xhf[bf][wv][lane] = hv;                                               \
        xlf[bf][wv][lane] = lv;                                               \
    }

    // compute role: wave wv owns col-tile ct = wv
    f32x4 acc = {0.f, 0.f, 0.f, 0.f};

    STAGE(0, 0);
    __syncthreads();

    for (int c = 0; c < 4; ++c) {
        const int cur = c & 1;
        if (c < 3) STAGE(c + 1, cur ^ 1);   // stage next chunk into other buf
#pragma unroll
        for (int kg = 0; kg < 8; ++kg) {
            const bf16x8 ah = *reinterpret_cast<const bf16x8*>(&xhf[cur][kg][lane]);
            const bf16x8 al = *reinterpret_cast<const bf16x8*>(&xlf[cur][kg][lane]);
            const size_t wslot = ((size_t)wv * 32 + c * 8 + kg) * 64 + lane;
            const bf16x8 bh = *reinterpret_cast<const bf16x8*>(whf + wslot * 8);
            const bf16x8 bl = *reinterpret_cast<const bf16x8*>(wlf + wslot * 8);
            acc = __builtin_amdgcn_mfma_f32_16x16x32_bf16(ah, bh, acc, 0, 0, 0);
            acc = __builtin_amdgcn_mfma_f32_16x16x32_bf16(al, bh, acc, 0, 0, 0);
            acc = __builtin_amdgcn_mfma_f32_16x16x32_bf16(ah, bl, acc, 0, 0, 0);
            acc = __builtin_amdgcn_mfma_f32_16x16x32_bf16(al, bl, acc, 0, 0, 0);
        }
        __syncthreads();
    }
#undef STAGE

    // ---- epilogue: bias, f32 qk tile; C layout col=lane&15, row=(lane>>4)*4+r ----
    {
        const int cj = wv * 16 + (lane & 15);
        const int r0 = (lane >> 4) * 4;
        const float bv = (cj < DDIM) ? bq[cj] : bk[cj - DDIM];
        const int cb = (cj < DDIM) ? cj : (68 + cj - DDIM);
#pragma unroll
        for (int r = 0; r < 4; ++r)
            qk[(r0 + r) * QK_STRIDE + cb] = acc[r] + bv;
    }
    __syncthreads();

    // ---- phase 3 (verbatim r2/r5, proven): RNE hi/lo split to frag order ----
    if (tid < 256) {
        const int l2  = tid & 63;
        const int dc  = (tid >> 6) & 1;
        const int isK = tid >> 7;
        const int row = l2 & 15;
        const int d0  = dc * 32 + ((l2 >> 4) & 3) * 8;
        const float* p = &qk[row * QK_STRIDE + (isK ? 68 : 0) + d0];
        const float sc = isK ? 1.0f : 0.125f;   // fold 1/sqrt(D) into q
        u16x8 hvv, lvv;
#pragma unroll
        for (int j = 0; j < 8; ++j) {
            const float vq = p[j] * sc;
            const unsigned short h = f2bf(vq);
            hvv[j] = h;
            lvv[j] = f2bf(vq - bf2f(h));
        }
        const size_t base = ((((size_t)b * 256 + (size_t)(gt & 255)) * 2 + dc) * 512) + (size_t)l2 * 8;
        *reinterpret_cast<u16x8*>((isK ? khf : qhf) + base) = hvv;
        *reinterpret_cast<u16x8*>((isK ? klf : qlf) + base) = lvv;
    }
}

// ---------------- kernel S: QK^T + rowmax + exp (verbatim r2/r5) ----------------
__global__ __launch_bounds__(1024, 1) void score_kernel(
    const unsigned short* __restrict__ qhf, const unsigned short* __restrict__ qlf,
    const unsigned short* __restrict__ khf, const unsigned short* __restrict__ klf,
    float* __restrict__ out)
{
    __shared__ float wmax[16 * 16];
    __shared__ float fmax_s[16];
    const int tid = threadIdx.x;
    const int l   = tid & 63;
    const int w   = tid >> 6;        // wave 0..15, owns col-tiles w*16..w*16+15
    const int bid = blockIdx.x;
    const int b   = bid >> 8;
    const int rt  = bid & 255;       // row tile (16 q rows)

    const size_t abase = (((size_t)b * 256 + rt) * 2) * 512 + (size_t)l * 8;
    const bf16x8 qh0 = *reinterpret_cast<const bf16x8*>(qhf + abase);
    const bf16x8 qh1 = *reinterpret_cast<const bf16x8*>(qhf + abase + 512);
    const bf16x8 ql0 = *reinterpret_cast<const bf16x8*>(qlf + abase);
    const bf16x8 ql1 = *reinterpret_cast<const bf16x8*>(qlf + abase + 512);

    f32x4 acc[16];
#pragma unroll
    for (int i = 0; i < 16; ++i) acc[i] = (f32x4){0.f, 0.f, 0.f, 0.f};

#pragma unroll
    for (int i = 0; i < 16; ++i) {
        const int ct = w * 16 + i;
        const size_t kb = (((size_t)b * 256 + ct) * 2) * 512 + (size_t)l * 8;
        const bf16x8 kh0 = *reinterpret_cast<const bf16x8*>(khf + kb);
        const bf16x8 kh1 = *reinterpret_cast<const bf16x8*>(khf + kb + 512);
        const bf16x8 kl0 = *reinterpret_cast<const bf16x8*>(klf + kb);
        const bf16x8 kl1 = *reinterpret_cast<const bf16x8*>(klf + kb + 512);
        f32x4 a = acc[i];
        a = __builtin_amdgcn_mfma_f32_16x16x32_bf16(qh0, kh0, a, 0, 0, 0);
        a = __builtin_amdgcn_mfma_f32_16x16x32_bf16(qh1, kh1, a, 0, 0, 0);
        a = __builtin_amdgcn_mfma_f32_16x16x32_bf16(qh0, kl0, a, 0, 0, 0);
        a = __builtin_amdgcn_mfma_f32_16x16x32_bf16(qh1, kl1, a, 0, 0, 0);
        a = __builtin_amdgcn_mfma_f32_16x16x32_bf16(ql0, kh0, a, 0, 0, 0);
        a = __builtin_amdgcn_mfma_f32_16x16x32_bf16(ql1, kh1, a, 0, 0, 0);
        acc[i] = a;
    }

    float m4[4];
#pragma unroll
    for (int r = 0; r < 4; ++r) {
        m4[r] = acc[0][r];
#pragma unroll
        for (int i = 1; i < 16; ++i) m4[r] = fmaxf(m4[r], acc[i][r]);
    }
#pragma unroll
    for (int off = 1; off < 16; off <<= 1) {
#pragma unroll
        for (int r = 0; r < 4; ++r) m4[r] = fmaxf(m4[r], __shfl_xor(m4[r], off));
    }
    const int rgrp = l >> 4;
    if ((l & 15) == 0) {
#pragma unroll
        for (int r = 0; r < 4; ++r) wmax[w * 16 + rgrp * 4 + r] = m4[r];
    }
    __syncthreads();
    if (tid < 16) {
        float m = wmax[tid];
#pragma unroll
        for (int ww = 1; ww < 16; ++ww) m = fmaxf(m, wmax[ww * 16 + tid]);
        fmax_s[tid] = m;
    }
    __syncthreads();

    float fm[4];
#pragma unroll
    for (int r = 0; r < 4; ++r) fm[r] = fmax_s[rgrp * 4 + r];
    const int cres = l & 15;
    const size_t obase = ((size_t)b * SLEN + (size_t)rt * 16) * SLEN;
#pragma unroll
    for (int i = 0; i < 16; ++i) {
        const int col = (w * 16 + i) * 16 + cres;
#pragma unroll
        for (int r = 0; r < 4; ++r)
            out[obase + (size_t)(rgrp * 4 + r) * SLEN + col] = __expf(acc[i][r] - fm[r]);
    }
}

extern "C" void kernel_launch(void* const* d_in, const int* in_sizes, int n_in,
                              void* d_out, int out_size, void* d_ws, size_t ws_size,
                              hipStream_t stream) {
    (void)in_sizes; (void)n_in;
    const float* src   = (const float*)d_in[0];
    const float* gamma = (const float*)d_in[1];
    const float* beta  = (const float*)d_in[2];
    const float* Wq    = (const float*)d_in[3];
    const float* bq    = (const float*)d_in[4];
    const float* Wk    = (const float*)d_in[5];
    const float* bk    = (const float*)d_in[6];
    float* out = (float*)d_out;

    // ws: qhf/qlf/khf/klf 1 MB each; then whf/wlf 256 KB each (r5 scheme).
    unsigned short* ws  = (unsigned short*)d_ws;
    unsigned short* qhf = ws;
    unsigned short* qlf = ws + (1u << 19);
    unsigned short* khf = ws + (2u << 19);
    unsigned short* klf = ws + (3u << 19);

    const size_t wfrag_shorts = 131072;             // 256 KB each
    const size_t need_bytes = (4u << 20) + 2 * 256 * 1024;
    unsigned short *whf, *wlf;
    if (ws_size >= need_bytes) {
        whf = ws + (4u << 19);
        wlf = whf + wfrag_shorts;
    } else {
        // park W frags in d_out tail: wprep writes -> ln_proj reads ->
        // score overwrites every byte afterwards (stream-ordered).
        const size_t out_bytes = (size_t)out_size * 4;
        char* tail = (char*)d_out + (out_bytes - (2 * 256 * 1024 + 4096));
        whf = (unsigned short*)tail;
        wlf = whf + wfrag_shorts;
    }

    hipLaunchKernelGGL(wprep_kernel, dim3(64), dim3(256), 0, stream,
                       Wq, Wk, whf, wlf);
    hipLaunchKernelGGL(ln_proj_kernel, dim3(512), dim3(512), 0, stream,
                       src, gamma, beta, bq, bk, whf, wlf, qhf, qlf, khf, klf);
    hipLaunchKernelGGL(score_kernel, dim3(512), dim3(1024), 0, stream,
                       qhf, qlf, khf, klf, out);
}